// Round 6
// baseline (295.882 us; speedup 1.0000x reference)
//
#include <hip/hip_runtime.h>
#include <math.h>

// Problem constants (from reference setup_inputs)
#define NC 80            // NUM_CLASSES
constexpr int BS  = 16;      // batch
constexpr int NA  = 33600;   // anchors
constexpr int NG  = 64;      // gt boxes
constexpr int TPB = 256;
constexpr int NBLK = (NA + TPB - 1) / TPB;  // 132 blocks per batch
constexpr int NW   = TPB / 64;              // 4 waves per block
constexpr int NC4  = NC / 4;                // 20 float4 per score row

typedef float f32x4 __attribute__((ext_vector_type(4)));

// branchless insert of v into descending top-3 (t0 >= t1 >= t2): 6 VALU ops
__device__ __forceinline__ void ins3(float v, float& t0, float& t1, float& t2) {
  t2 = fmaxf(t2, fminf(v, t1));   // uses old t1
  t1 = fmaxf(t1, fminf(v, t0));   // uses old t0
  t0 = fmaxf(t0, v);
}

// 64-lane butterfly top3 merge
__device__ __forceinline__ void wave_top3(float& t0, float& t1, float& t2) {
  #pragma unroll
  for (int off = 32; off > 0; off >>= 1) {
    float u0 = __shfl_xor(t0, off, 64);
    float u1 = __shfl_xor(t1, off, 64);
    float u2 = __shfl_xor(t2, off, 64);
    ins3(u0, t0, t1, t2);
    ins3(u1, t0, t1, t2);
    ins3(u2, t0, t1, t2);
  }
}

// ---------------------------------------------------------------------------
// P1: fused main pass, ZERO-FIRST wave-local one-hot. R4/R5 established the
// single-pass coalesced emit and removed the block barrier; this round
// fixes the last serialization: the emit could not start until the IoU
// argmax finished (the shfl-compare needed the final class), so the 80 KB
// store stream trailed the divide chain instead of overlapping it. Now each
// wave stores its 20 KB of ZEROS right after the GT barrier (no shfl, no
// compares — the one-hot is 0 everywhere except <=1 word/row), the IoU loop
// runs while those stores drain, and after the per-anchor outputs a
// WAVE-LOCAL `s_waitcnt vmcnt(0)` (inline asm, ~free by then, blocks no
// other wave) orders the single 1.0f scatter per foreground row over its
// zero. Same-address store-after-store is exact: the scatter issues only
// after all prior stores completed. IoU loop: exact IEEE divide, every
// comparison bit-identical to numpy. Deferred top-3 behind the wave-uniform
// wmax<=0.3 gate (global fallback implies ALL waves take it -> triples the
// slow consumer reads are always fresh). blockTop slot 0 carries wmax
// (== t0 on the slow path); footprint exactly BS*NBLK*NW*3 floats.
// Invalid GT boxes are zeroed in LDS so their IoU is exactly 0.0.
// ---------------------------------------------------------------------------
__global__ __launch_bounds__(TPB) void p1_kernel(
    const float4* __restrict__ pd, const float4* __restrict__ gt,
    const int* __restrict__ glab, const int* __restrict__ gmask,
    float* __restrict__ outL, float4* __restrict__ outB,
    float* __restrict__ outS, float* __restrict__ outF,
    float* __restrict__ outI, float* __restrict__ blockTop)
{
  #pragma clang fp contract(off)
  const int b   = blockIdx.y;
  const int tid = threadIdx.x;

  __shared__ float4 sbox[NG];
  __shared__ float  sarea[NG];
  __shared__ int    slab[NG];
  __shared__ int    svalid[NG];

  const int a0  = blockIdx.x * TPB;
  const int a   = a0 + tid;
  const bool inb = a < NA;
  const int lane = tid & 63, wid = tid >> 6;

  // ---- own pd box (issued before the barrier) ----
  float4 p = make_float4(0.f, 0.f, 0.f, 0.f);
  if (inb) p = pd[(long)b * NA + a];

  // ---- stage gt into LDS ----
  if (tid < NG) {
    int v = gmask[b * NG + tid];
    float4 g = gt[b * NG + tid];
    if (!v) g = make_float4(0.f, 0.f, 0.f, 0.f);  // zero-box => iou == 0
    sbox[tid]   = g;
    sarea[tid]  = (g.z - g.x) * (g.w - g.y);
    slab[tid]   = glab[b * NG + tid];
    svalid[tid] = v;
  }
  __syncthreads();   // the ONLY barrier; issued before any of our stores

  // ---- zero-emit: wave w streams zeros over its own 64 score rows NOW,
  // so the 20 KB/wave store drain overlaps the IoU divide chain below.
  // Coalesced 64x16B lines, nontemporal (outS is never re-read). ----
  const int nA    = min(TPB, NA - a0);
  const int wrow0 = wid * 64;                   // wave's first local row
  const int rows  = min(64, nA - wrow0);        // <=0 for fully-OOB waves
  f32x4* s4 = reinterpret_cast<f32x4*>(outS + ((long)b * NA + a0 + wrow0) * NC);
  if (rows > 0) {
    const int cnt4 = rows * NC4;
    f32x4 z = {0.f, 0.f, 0.f, 0.f};
    #pragma unroll 5
    for (int i = lane; i < cnt4; i += 64)
      __builtin_nontemporal_store(z, s4 + i);
  }

  float best = -1.f;
  int   bidx = 0;
  float a2 = 0.f;
  bool  maskv = false;
  int   blab  = 0;

  if (inb) {
    a2 = (p.z - p.x) * (p.w - p.y);
    #pragma unroll 8
    for (int g = 0; g < NG; ++g) {
      float4 gb = sbox[g];
      float iw = fminf(gb.z, p.z) - fmaxf(gb.x, p.x);
      float ih = fminf(gb.w, p.w) - fmaxf(gb.y, p.y);
      iw = fmaxf(iw, 0.f);
      ih = fmaxf(ih, 0.f);
      float inter = iw * ih;
      float den   = sarea[g] + a2 - inter + 1e-9f;
      float iou   = inter / den;                 // exact IEEE, matches np
      bidx = (iou > best) ? g : bidx;            // first-index tie-break
      best = fmaxf(best, iou);
    }
    bool fg = best > 0.3f;
    maskv = fg && (svalid[bidx] != 0);
    blab  = slab[bidx];
    long ga = (long)b * NA + a;
    outL[ga] = maskv ? (float)blab : 80.f;       // BG_IDX = 80
    float m = maskv ? 1.f : 0.f;
    float4 gb = sbox[bidx];
    outB[ga] = make_float4(gb.x * m, gb.y * m, gb.z * m, gb.w * m);
    outF[ga] = fg ? 1.f : 0.f;
    outI[ga] = (float)bidx;
  }

  // ---- per-wave max of best (cheap: 6 shfl + 6 fmax) ----
  float wmax = best;
  #pragma unroll
  for (int off = 32; off > 0; off >>= 1)
    wmax = fmaxf(wmax, __shfl_xor(wmax, off, 64));

  float* bt = blockTop + (((long)b * NBLK + blockIdx.x) * NW + wid) * 3;

  // ---- rare path: this wave cannot prove fg. Recompute ious with full
  // top-3 tracking and publish the triple's tail. Global need_fb implies
  // ALL waves land here, so the triples the slow consumer reads are always
  // freshly written. (OOB tail waves publish -inf tails and wmax=-1 — both
  // below any real iou >= 0, so the batch top-3, always >= 0 with 33600
  // real anchors, is unaffected.) ----
  if (wmax <= 0.3f) {                            // wave-uniform branch
    float t0 = -INFINITY, t1 = -INFINITY, t2 = -INFINITY;
    if (inb) {
      #pragma unroll 4
      for (int g = 0; g < NG; ++g) {
        float4 gb = sbox[g];
        float iw = fminf(gb.z, p.z) - fmaxf(gb.x, p.x);
        float ih = fminf(gb.w, p.w) - fmaxf(gb.y, p.y);
        iw = fmaxf(iw, 0.f);
        ih = fmaxf(ih, 0.f);
        float inter = iw * ih;
        float den   = sarea[g] + a2 - inter + 1e-9f;
        float iou   = inter / den;
        ins3(iou, t0, t1, t2);
      }
    }
    wave_top3(t0, t1, t2);
    if (lane == 0) { bt[1] = t1; bt[2] = t2; }
  }
  // ---- unconditional per-wave max (slot 0; t0 == wmax on the slow path) ----
  if (lane == 0) bt[0] = wmax;

  // ---- wave-local drain: all prior stores (the zero stream, long since
  // in flight) complete before the one-hot scatter overwrites its word.
  // No effect on other waves; ~free after ~3000 cycles of IoU compute. ----
  asm volatile("s_waitcnt vmcnt(0)" ::: "memory");
  if (inb && maskv) outS[((long)b * NA + a) * NC + blab] = 1.f;
}

// ---------------------------------------------------------------------------
// P3: fallback fixup, ONE BLOCK PER BATCH (grid = BS). Fast path: reduce
// max over this batch's per-wave maxima (528 stride-3 floats, L2-hot) and
// exit uniformly. Cold path (never taken on this data, kept correct):
// ballot over gmask, full top-3 reduce of blockTop triples for min_iou,
// then a grid-stride loop over all NA anchors doing the rewrite + one-hot
// scatter from this single block. need_fb implies P1 wrote the batch
// entirely as background (scores all zero), so only rewrites are needed;
// target_gt_idx is fallback-independent -> untouched.
// ---------------------------------------------------------------------------
__global__ __launch_bounds__(TPB) void p3_kernel(
    const float4* __restrict__ pd, const float4* __restrict__ gt,
    const int* __restrict__ glab, const int* __restrict__ gmask,
    const float* __restrict__ blockTop,
    float* __restrict__ outL, float4* __restrict__ outB,
    float* __restrict__ outS, float* __restrict__ outF)
{
  #pragma clang fp contract(off)
  const int b   = blockIdx.x;
  const int tid = threadIdx.x;

  __shared__ float  swm[NW];
  __shared__ float  sM;
  __shared__ float  swt[NW][3];
  __shared__ float  sres;
  __shared__ int    sfb;
  __shared__ float4 sbox[NG];
  __shared__ float  sarea[NG];
  __shared__ int    slab[NG];
  __shared__ int    svalid[NG];

  // ---- fast decision: max over this batch's per-wave maxima (slot 0) ----
  float m = -INFINITY;
  for (int i = tid; i < NBLK * NW; i += TPB)
    m = fmaxf(m, blockTop[((long)b * NBLK * NW + i) * 3]);
  #pragma unroll
  for (int off = 32; off > 0; off >>= 1)
    m = fmaxf(m, __shfl_xor(m, off, 64));
  const int lane = tid & 63, wid = tid >> 6;
  if (lane == 0) swm[wid] = m;
  __syncthreads();
  if (tid == 0) {
    float r = swm[0];
    #pragma unroll
    for (int w = 1; w < NW; ++w) r = fmaxf(r, swm[w]);
    sM = r;
  }
  __syncthreads();
  if (sM > 0.3f) return;       // common case: batch has fg -> uniform exit

  // ================= slow path (cold, correctness only) =================
  int gv = (tid < NG) ? gmask[b * NG + tid] : 0;
  unsigned long long bal = __ballot(gv != 0);  // valid in wave 0

  // reduce batch's per-wave top3 triples (all freshly written: global
  // fallback implies every p1 wave took the rare path)
  float t0 = -INFINITY, t1 = -INFINITY, t2 = -INFINITY;
  for (int i = tid; i < NBLK * NW; i += TPB) {
    const float* bt = blockTop + ((long)b * NBLK * NW + i) * 3;
    ins3(bt[0], t0, t1, t2);
    ins3(bt[1], t0, t1, t2);
    ins3(bt[2], t0, t1, t2);
  }
  wave_top3(t0, t1, t2);
  if (lane == 0) { swt[wid][0] = t0; swt[wid][1] = t1; swt[wid][2] = t2; }
  __syncthreads();
  if (tid == 0) {
    float r0 = swt[0][0], r1 = swt[0][1], r2 = swt[0][2];
    #pragma unroll
    for (int w = 1; w < NW; ++w) {
      ins3(swt[w][0], r0, r1, r2);
      ins3(swt[w][1], r0, r1, r2);
      ins3(swt[w][2], r0, r1, r2);
    }
    sfb  = (!(r0 > 0.3f) && bal != 0ULL) ? 1 : 0;
    sres = r2;
  }
  // stage gt into LDS (overlaps the decision barrier)
  if (tid < NG) {
    float4 g = gt[b * NG + tid];
    if (!gv) g = make_float4(0.f, 0.f, 0.f, 0.f);
    sbox[tid]   = g;
    sarea[tid]  = (g.z - g.x) * (g.w - g.y);
    slab[tid]   = glab[b * NG + tid];
    svalid[tid] = gv;
  }
  __syncthreads();
  if (sfb == 0) return;        // uniform exit (no barriers after this)
  const float minio = sres;

  // grid-stride rewrite of the whole batch from this single block (cold)
  for (int a = tid; a < NA; a += TPB) {
    float4 p  = pd[(long)b * NA + a];
    float  a2 = (p.z - p.x) * (p.w - p.y);
    float best = -1.f;
    int   bidx = 0;
    #pragma unroll 8
    for (int g = 0; g < NG; ++g) {
      float4 gb = sbox[g];
      float iw = fminf(gb.z, p.z) - fmaxf(gb.x, p.x);
      float ih = fminf(gb.w, p.w) - fmaxf(gb.y, p.y);
      iw = fmaxf(iw, 0.f);
      ih = fmaxf(ih, 0.f);
      float inter = iw * ih;
      float den   = sarea[g] + a2 - inter + 1e-9f;
      float iou   = inter / den;
      bidx = (iou > best) ? g : bidx;
      best = fmaxf(best, iou);
    }
    // fallback fg: max over valid of overlaps >= min_iou. With zero-boxes
    // and has_valid guaranteed here, max over all g == max over valid g.
    bool fg    = best >= minio;
    bool maskv = fg && (svalid[bidx] != 0);
    int  blab  = slab[bidx];
    long ga = (long)b * NA + a;
    outL[ga] = maskv ? (float)blab : 80.f;
    float mm = maskv ? 1.f : 0.f;
    float4 gb = sbox[bidx];
    outB[ga] = make_float4(gb.x * mm, gb.y * mm, gb.z * mm, gb.w * mm);
    outF[ga] = fg ? 1.f : 0.f;
    if (maskv) outS[ga * NC + blab] = 1.f;  // scores were all-zero here
  }
}

// ---------------------------------------------------------------------------
// launch
// ---------------------------------------------------------------------------
extern "C" void kernel_launch(void* const* d_in, const int* in_sizes, int n_in,
                              void* d_out, int out_size, void* d_ws, size_t ws_size,
                              hipStream_t stream) {
  // inputs (setup_inputs order): 0 pd_scores (unused), 1 pd_bboxes,
  // 2 anc_points (unused), 3 gt_labels, 4 gt_bboxes, 5 mask_gt
  const float4* pd    = (const float4*)d_in[1];
  const int*    glab  = (const int*)d_in[3];
  const float4* gt    = (const float4*)d_in[4];
  const int*    gmask = (const int*)d_in[5];

  float* outf = (float*)d_out;
  // outputs concatenated flat in return order (all as float32):
  // target_labels [16,33600], target_bboxes [16,33600,4],
  // target_scores [16,33600,80], fg_mask [16,33600], target_gt_idx [16,33600]
  float*  outL = outf;
  float4* outB = (float4*)(outf + (long)BS * NA);
  float*  outS = outf + (long)BS * NA * 5;
  float*  outF = outf + (long)BS * NA * 5 + (long)BS * NA * NC;
  float*  outI = outF + (long)BS * NA;

  // workspace: per-wave {max, top3-tail} triples — exactly the proven
  // BS*NBLK*NW*3 floats (~101 KB), no growth vs the verified baseline.
  float* blockTop = (float*)d_ws;

  dim3 grid(NBLK, BS);
  p1_kernel<<<grid, TPB, 0, stream>>>(pd, gt, glab, gmask,
                                      outL, outB, outS, outF, outI, blockTop);
  p3_kernel<<<BS, TPB, 0, stream>>>(pd, gt, glab, gmask, blockTop,
                                    outL, outB, outS, outF);
}

// Round 7
// 288.810 us; speedup vs baseline: 1.0245x; 1.0245x over previous
//
#include <hip/hip_runtime.h>
#include <math.h>

// Problem constants (from reference setup_inputs)
#define NC 80            // NUM_CLASSES
constexpr int BS  = 16;      // batch
constexpr int NA  = 33600;   // anchors
constexpr int NG  = 64;      // gt boxes
constexpr int TPB = 256;
constexpr int NBLK = (NA + TPB - 1) / TPB;  // 132 logical chunks per batch
constexpr int CPB  = 2;                     // chunks per block
constexpr int NBLK2 = NBLK / CPB;           // 66 blocks per batch (132 = 66*2)
constexpr int NW   = TPB / 64;              // 4 waves per block
constexpr int NC4  = NC / 4;                // 20 float4 per score row

typedef float f32x4 __attribute__((ext_vector_type(4)));

// branchless insert of v into descending top-3 (t0 >= t1 >= t2): 6 VALU ops
__device__ __forceinline__ void ins3(float v, float& t0, float& t1, float& t2) {
  t2 = fmaxf(t2, fminf(v, t1));   // uses old t1
  t1 = fmaxf(t1, fminf(v, t0));   // uses old t0
  t0 = fmaxf(t0, v);
}

// 64-lane butterfly top3 merge
__device__ __forceinline__ void wave_top3(float& t0, float& t1, float& t2) {
  #pragma unroll
  for (int off = 32; off > 0; off >>= 1) {
    float u0 = __shfl_xor(t0, off, 64);
    float u1 = __shfl_xor(t1, off, 64);
    float u2 = __shfl_xor(t2, off, 64);
    ins3(u0, t0, t1, t2);
    ins3(u1, t0, t1, t2);
    ins3(u2, t0, t1, t2);
  }
}

// ---------------------------------------------------------------------------
// P1: fused main pass, 2 CHUNKS PER BLOCK. R4-R6 established the single-pass
// inline one-hot emit (R5, best) and showed zero-first reordering is neutral
// after machine-speed calibration. This round halves the replicated per-block
// overhead (GT staging + barrier + ramp: 2112 -> 1056 instances) by having
// each block process two consecutive 256-anchor chunks off ONE staged GT
// tile, R5 flow per chunk. Side benefit: chunk 0's 20 KB emit burst drains
// under chunk 1's IoU divide chain — fill-behind-compute with zero ordering
// hazard (each outS byte still written exactly once, value computed inline).
// IoU loop: exact IEEE divide, every comparison bit-identical to numpy.
// Deferred top-3 behind the wave-uniform wmax<=0.3 gate per chunk (global
// fallback implies ALL ious <= 0.3, so every chunk-wave takes the gate and
// the triples p3 reads are always fresh). blockTop keeps the [b][132][4][3]
// layout (logical chunk = blockIdx.x*2+c); slot 0 carries wmax (== t0 on
// the slow path). Invalid GT boxes are zeroed in LDS so their IoU is 0.0.
// ---------------------------------------------------------------------------
__global__ __launch_bounds__(TPB) void p1_kernel(
    const float4* __restrict__ pd, const float4* __restrict__ gt,
    const int* __restrict__ glab, const int* __restrict__ gmask,
    float* __restrict__ outL, float4* __restrict__ outB,
    float* __restrict__ outS, float* __restrict__ outF,
    float* __restrict__ outI, float* __restrict__ blockTop)
{
  #pragma clang fp contract(off)
  const int b   = blockIdx.y;
  const int tid = threadIdx.x;

  __shared__ float4 sbox[NG];
  __shared__ float  sarea[NG];
  __shared__ int    slab[NG];
  __shared__ int    svalid[NG];

  const int lane = tid & 63, wid = tid >> 6;
  const int cbase = blockIdx.x * CPB;          // first logical chunk index

  // ---- prefetch own pd box for BOTH chunks (issued before the barrier) ----
  float4 pv[CPB];
  int    av[CPB];
  bool   ib[CPB];
  #pragma unroll
  for (int c = 0; c < CPB; ++c) {
    av[c] = (cbase + c) * TPB + tid;
    ib[c] = av[c] < NA;
    pv[c] = make_float4(0.f, 0.f, 0.f, 0.f);
    if (ib[c]) pv[c] = pd[(long)b * NA + av[c]];
  }

  // ---- stage gt into LDS (once, serves both chunks) ----
  if (tid < NG) {
    int v = gmask[b * NG + tid];
    float4 g = gt[b * NG + tid];
    if (!v) g = make_float4(0.f, 0.f, 0.f, 0.f);  // zero-box => iou == 0
    sbox[tid]   = g;
    sarea[tid]  = (g.z - g.x) * (g.w - g.y);
    slab[tid]   = glab[b * NG + tid];
    svalid[tid] = v;
  }
  __syncthreads();   // the ONLY barrier

  #pragma unroll
  for (int c = 0; c < CPB; ++c) {
    const int   a   = av[c];
    const bool  inb = ib[c];
    const float4 p  = pv[c];
    const int   a0  = (cbase + c) * TPB;       // chunk anchor base

    float best = -1.f;
    int   bidx = 0;
    float a2 = 0.f;
    bool  maskv = false;
    int   blab  = 0;

    if (inb) {
      a2 = (p.z - p.x) * (p.w - p.y);
      #pragma unroll 8
      for (int g = 0; g < NG; ++g) {
        float4 gb = sbox[g];
        float iw = fminf(gb.z, p.z) - fmaxf(gb.x, p.x);
        float ih = fminf(gb.w, p.w) - fmaxf(gb.y, p.y);
        iw = fmaxf(iw, 0.f);
        ih = fmaxf(ih, 0.f);
        float inter = iw * ih;
        float den   = sarea[g] + a2 - inter + 1e-9f;
        float iou   = inter / den;               // exact IEEE, matches np
        bidx = (iou > best) ? g : bidx;          // first-index tie-break
        best = fmaxf(best, iou);
      }
      bool fg = best > 0.3f;
      maskv = fg && (svalid[bidx] != 0);
      blab  = slab[bidx];
      long ga = (long)b * NA + a;
      outL[ga] = maskv ? (float)blab : 80.f;     // BG_IDX = 80
      float m = maskv ? 1.f : 0.f;
      float4 gb = sbox[bidx];
      outB[ga] = make_float4(gb.x * m, gb.y * m, gb.z * m, gb.w * m);
      outF[ga] = fg ? 1.f : 0.f;
      outI[ga] = (float)bidx;
    }

    // ---- wave-local one-hot emit: wave w owns rows [w*64, w*64+64) of
    // this chunk's score tile; each row's class comes from the owning lane
    // via shfl. No barrier, no LDS — stores issue as soon as this wave's
    // IoU loop retires, and (for c=0) drain under chunk 1's IoU compute.
    // Coalesced 64x16B lines, nontemporal (outS is never re-read). ----
    const int nA    = min(TPB, NA - a0);
    const int wrow0 = wid * 64;                  // wave's first local row
    const int rows  = min(64, nA - wrow0);       // <=0 for fully-OOB waves
    const int own_cls = maskv ? blab : -1;       // -1 = background
    if (rows > 0) {
      f32x4* s4 = reinterpret_cast<f32x4*>(outS + ((long)b * NA + a0 + wrow0) * NC);
      const int cnt4 = rows * NC4;
      for (int i = lane; i < cnt4; i += 64) {
        int row = i / NC4;               // magic-mul div by 20
        int c0  = (i - row * NC4) * 4;   // starting class of this float4
        int cls = __shfl(own_cls, row, 64);
        f32x4 v;
        v.x = (cls == c0    ) ? 1.f : 0.f;
        v.y = (cls == c0 + 1) ? 1.f : 0.f;
        v.z = (cls == c0 + 2) ? 1.f : 0.f;
        v.w = (cls == c0 + 3) ? 1.f : 0.f;
        __builtin_nontemporal_store(v, s4 + i);
      }
    }

    // ---- per-wave max of best (cheap: 6 shfl + 6 fmax) ----
    float wmax = best;
    #pragma unroll
    for (int off = 32; off > 0; off >>= 1)
      wmax = fmaxf(wmax, __shfl_xor(wmax, off, 64));

    float* bt = blockTop + (((long)b * NBLK + (cbase + c)) * NW + wid) * 3;

    // ---- rare path: this wave cannot prove fg. Recompute ious with full
    // top-3 tracking and publish the triple's tail. Global need_fb implies
    // ALL chunk-waves land here, so the triples the slow consumer reads
    // are always freshly written. (OOB tail waves publish -inf tails and
    // wmax=-1 — both below any real iou >= 0, so the batch top-3, always
    // >= 0 with 33600 real anchors, is unaffected.) ----
    if (wmax <= 0.3f) {                          // wave-uniform branch
      float t0 = -INFINITY, t1 = -INFINITY, t2 = -INFINITY;
      if (inb) {
        #pragma unroll 4
        for (int g = 0; g < NG; ++g) {
          float4 gb = sbox[g];
          float iw = fminf(gb.z, p.z) - fmaxf(gb.x, p.x);
          float ih = fminf(gb.w, p.w) - fmaxf(gb.y, p.y);
          iw = fmaxf(iw, 0.f);
          ih = fmaxf(ih, 0.f);
          float inter = iw * ih;
          float den   = sarea[g] + a2 - inter + 1e-9f;
          float iou   = inter / den;
          ins3(iou, t0, t1, t2);
        }
      }
      wave_top3(t0, t1, t2);
      if (lane == 0) { bt[1] = t1; bt[2] = t2; }
    }
    // ---- unconditional per-wave max (slot 0; t0 == wmax slow-path) ----
    if (lane == 0) bt[0] = wmax;
  }
}

// ---------------------------------------------------------------------------
// P3: fallback fixup, ONE BLOCK PER BATCH (grid = BS). Fast path: reduce
// max over this batch's per-wave maxima (528 stride-3 floats, L2-hot) and
// exit uniformly. Cold path (never taken on this data, kept correct):
// ballot over gmask, full top-3 reduce of blockTop triples for min_iou,
// then a grid-stride loop over all NA anchors doing the rewrite + one-hot
// scatter from this single block. need_fb implies P1 wrote the batch
// entirely as background (scores all zero), so only rewrites are needed;
// target_gt_idx is fallback-independent -> untouched.
// ---------------------------------------------------------------------------
__global__ __launch_bounds__(TPB) void p3_kernel(
    const float4* __restrict__ pd, const float4* __restrict__ gt,
    const int* __restrict__ glab, const int* __restrict__ gmask,
    const float* __restrict__ blockTop,
    float* __restrict__ outL, float4* __restrict__ outB,
    float* __restrict__ outS, float* __restrict__ outF)
{
  #pragma clang fp contract(off)
  const int b   = blockIdx.x;
  const int tid = threadIdx.x;

  __shared__ float  swm[NW];
  __shared__ float  sM;
  __shared__ float  swt[NW][3];
  __shared__ float  sres;
  __shared__ int    sfb;
  __shared__ float4 sbox[NG];
  __shared__ float  sarea[NG];
  __shared__ int    slab[NG];
  __shared__ int    svalid[NG];

  // ---- fast decision: max over this batch's per-wave maxima (slot 0) ----
  float m = -INFINITY;
  for (int i = tid; i < NBLK * NW; i += TPB)
    m = fmaxf(m, blockTop[((long)b * NBLK * NW + i) * 3]);
  #pragma unroll
  for (int off = 32; off > 0; off >>= 1)
    m = fmaxf(m, __shfl_xor(m, off, 64));
  const int lane = tid & 63, wid = tid >> 6;
  if (lane == 0) swm[wid] = m;
  __syncthreads();
  if (tid == 0) {
    float r = swm[0];
    #pragma unroll
    for (int w = 1; w < NW; ++w) r = fmaxf(r, swm[w]);
    sM = r;
  }
  __syncthreads();
  if (sM > 0.3f) return;       // common case: batch has fg -> uniform exit

  // ================= slow path (cold, correctness only) =================
  int gv = (tid < NG) ? gmask[b * NG + tid] : 0;
  unsigned long long bal = __ballot(gv != 0);  // valid in wave 0

  // reduce batch's per-wave top3 triples (all freshly written: global
  // fallback implies every p1 chunk-wave took the rare path)
  float t0 = -INFINITY, t1 = -INFINITY, t2 = -INFINITY;
  for (int i = tid; i < NBLK * NW; i += TPB) {
    const float* bt = blockTop + ((long)b * NBLK * NW + i) * 3;
    ins3(bt[0], t0, t1, t2);
    ins3(bt[1], t0, t1, t2);
    ins3(bt[2], t0, t1, t2);
  }
  wave_top3(t0, t1, t2);
  if (lane == 0) { swt[wid][0] = t0; swt[wid][1] = t1; swt[wid][2] = t2; }
  __syncthreads();
  if (tid == 0) {
    float r0 = swt[0][0], r1 = swt[0][1], r2 = swt[0][2];
    #pragma unroll
    for (int w = 1; w < NW; ++w) {
      ins3(swt[w][0], r0, r1, r2);
      ins3(swt[w][1], r0, r1, r2);
      ins3(swt[w][2], r0, r1, r2);
    }
    sfb  = (!(r0 > 0.3f) && bal != 0ULL) ? 1 : 0;
    sres = r2;
  }
  // stage gt into LDS (overlaps the decision barrier)
  if (tid < NG) {
    float4 g = gt[b * NG + tid];
    if (!gv) g = make_float4(0.f, 0.f, 0.f, 0.f);
    sbox[tid]   = g;
    sarea[tid]  = (g.z - g.x) * (g.w - g.y);
    slab[tid]   = glab[b * NG + tid];
    svalid[tid] = gv;
  }
  __syncthreads();
  if (sfb == 0) return;        // uniform exit (no barriers after this)
  const float minio = sres;

  // grid-stride rewrite of the whole batch from this single block (cold)
  for (int a = tid; a < NA; a += TPB) {
    float4 p  = pd[(long)b * NA + a];
    float  a2 = (p.z - p.x) * (p.w - p.y);
    float best = -1.f;
    int   bidx = 0;
    #pragma unroll 8
    for (int g = 0; g < NG; ++g) {
      float4 gb = sbox[g];
      float iw = fminf(gb.z, p.z) - fmaxf(gb.x, p.x);
      float ih = fminf(gb.w, p.w) - fmaxf(gb.y, p.y);
      iw = fmaxf(iw, 0.f);
      ih = fmaxf(ih, 0.f);
      float inter = iw * ih;
      float den   = sarea[g] + a2 - inter + 1e-9f;
      float iou   = inter / den;
      bidx = (iou > best) ? g : bidx;
      best = fmaxf(best, iou);
    }
    // fallback fg: max over valid of overlaps >= min_iou. With zero-boxes
    // and has_valid guaranteed here, max over all g == max over valid g.
    bool fg    = best >= minio;
    bool maskv = fg && (svalid[bidx] != 0);
    int  blab  = slab[bidx];
    long ga = (long)b * NA + a;
    outL[ga] = maskv ? (float)blab : 80.f;
    float mm = maskv ? 1.f : 0.f;
    float4 gb = sbox[bidx];
    outB[ga] = make_float4(gb.x * mm, gb.y * mm, gb.z * mm, gb.w * mm);
    outF[ga] = fg ? 1.f : 0.f;
    if (maskv) outS[ga * NC + blab] = 1.f;  // scores were all-zero here
  }
}

// ---------------------------------------------------------------------------
// launch
// ---------------------------------------------------------------------------
extern "C" void kernel_launch(void* const* d_in, const int* in_sizes, int n_in,
                              void* d_out, int out_size, void* d_ws, size_t ws_size,
                              hipStream_t stream) {
  // inputs (setup_inputs order): 0 pd_scores (unused), 1 pd_bboxes,
  // 2 anc_points (unused), 3 gt_labels, 4 gt_bboxes, 5 mask_gt
  const float4* pd    = (const float4*)d_in[1];
  const int*    glab  = (const int*)d_in[3];
  const float4* gt    = (const float4*)d_in[4];
  const int*    gmask = (const int*)d_in[5];

  float* outf = (float*)d_out;
  // outputs concatenated flat in return order (all as float32):
  // target_labels [16,33600], target_bboxes [16,33600,4],
  // target_scores [16,33600,80], fg_mask [16,33600], target_gt_idx [16,33600]
  float*  outL = outf;
  float4* outB = (float4*)(outf + (long)BS * NA);
  float*  outS = outf + (long)BS * NA * 5;
  float*  outF = outf + (long)BS * NA * 5 + (long)BS * NA * NC;
  float*  outI = outF + (long)BS * NA;

  // workspace: per-wave {max, top3-tail} triples — exactly the proven
  // BS*NBLK*NW*3 floats (~101 KB) in the same [b][132][4][3] layout.
  float* blockTop = (float*)d_ws;

  dim3 grid(NBLK2, BS);
  p1_kernel<<<grid, TPB, 0, stream>>>(pd, gt, glab, gmask,
                                      outL, outB, outS, outF, outI, blockTop);
  p3_kernel<<<BS, TPB, 0, stream>>>(pd, gt, glab, gmask, blockTop,
                                    outL, outB, outS, outF);
}